// Round 6
// baseline (169.042 us; speedup 1.0000x reference)
//
#include <hip/hip_runtime.h>
#include <math.h>

#define NRAYS 512
#define NSAMP 64
#define IMH 480
#define IMW 640
#define NFEAT 256
#define ZNEAR 0.7f
#define ZFAR 1.5f
#define KU1 288          // W1 row length (ushorts): 0-8 meta, 9-15 zero, 16-271 feats, 272-287 zero
#define W1LO 36864       // ushort offset of W1 lo plane
#define W2OF 73728       // ushort offset of W2 hi plane
#define W2LO 16384       // relative ushort offset of W2 lo plane
#define H1S 264          // h1 LDS row stride (ushorts): hi[128] | lo[128] | pad[8]

typedef __attribute__((ext_vector_type(8))) short bf16x8;
typedef __attribute__((ext_vector_type(4))) float f32x4;

__device__ __forceinline__ unsigned short bf16rne(float f) {
    unsigned int u = __builtin_bit_cast(unsigned int, f);
    unsigned int r = (u + 0x7FFFu + ((u >> 16) & 1u)) >> 16;
    return (unsigned short)r;
}
__device__ __forceinline__ float bf16tof(unsigned short h) {
    unsigned int u = ((unsigned int)h) << 16;
    return __builtin_bit_cast(float, u);
}
__device__ __forceinline__ void splitpack(const float* f, bf16x8& hi, bf16x8& lo) {
    union { bf16x8 v; unsigned short u[8]; } H, L;
    #pragma unroll
    for (int i = 0; i < 8; ++i) {
        const unsigned short h = bf16rne(f[i]);
        H.u[i] = h;
        L.u[i] = bf16rne(f[i] - bf16tof(h));
    }
    hi = H.v; lo = L.v;
}

// ---- prep: transpose + bf16-split W1 -> [128][288] (k-map: 0-8 meta, 16-271 feats) and W2 ----
__global__ __launch_bounds__(256)
void nerf_prep(const float* __restrict__ W1, const float* __restrict__ W2,
               unsigned short* __restrict__ wsu) {
    const int i = blockIdx.x * 256 + threadIdx.x;
    if (i < 36864) {
        const int n = i / KU1, k = i % KU1;
        float val = 0.0f;
        if (k < 9) val = W1[k * 128 + n];
        else if (k >= 16 && k < 272) val = W1[(k - 7) * 128 + n];
        const unsigned short h = bf16rne(val);
        wsu[n * KU1 + k] = h;
        wsu[W1LO + n * KU1 + k] = bf16rne(val - bf16tof(h));
    } else if (i < 53248) {
        const int j = i - 36864;
        const int n = j >> 7, k = j & 127;
        const float val = W2[k * 128 + n];
        const unsigned short h = bf16rne(val);
        wsu[W2OF + n * 128 + k] = h;
        wsu[W2OF + W2LO + n * 128 + k] = bf16rne(val - bf16tof(h));
    }
}

// ---- main: block = (ray,view), 256 thr = 4 waves, wave owns 16 samples.
// Lane (l15,lg) bilerps ITS OWN A-fragment dims straight from feats into
// registers (no x-LDS at all). h1 is wave-private split-bf16 in LDS.
// One barrier total; 3-pass split-bf16 MFMA MLP; readout via shfl reduce.
__global__ __launch_bounds__(256, 3)
void nerf_main(const float* __restrict__ rayo,
               const float* __restrict__ rayd,
               const float* __restrict__ images,
               const float* __restrict__ intr,
               const float* __restrict__ einv,
               const float* __restrict__ feats,
               const float* __restrict__ b1,
               const float* __restrict__ b2,
               const float* __restrict__ Wr,
               const unsigned short* __restrict__ wsu,
               float* __restrict__ pf) {
    __shared__ float s_meta[NSAMP][12];          // int4 o4 | wx wy | cam xyz
    __shared__ float s_cdir[4];
    __shared__ unsigned short h1u[NSAMP * H1S];  // 33,792 B

    const int t = threadIdx.x;
    const int bid = blockIdx.x;
    const int r = bid >> 1, v = bid & 1;
    const int lane = t & 63;
    const int wid = __builtin_amdgcn_readfirstlane(t >> 6);
    const int l15 = lane & 15;
    const int lg  = lane >> 4;
    constexpr float STEP = (ZFAR - ZNEAR) / (NSAMP - 1);

    // ---- projection prep: one thread per sample ----
    if (t < NSAMP) {
        const int p = t;
        const float ox = rayo[r*3+0], oy = rayo[r*3+1], oz = rayo[r*3+2];
        const float dx = rayd[r*3+0], dy = rayd[r*3+1], dz = rayd[r*3+2];
        const float z = ZNEAR + p * STEP;
        const float wxp = ox + z*dx, wyp = oy + z*dy, wzp = oz + z*dz;
        const float* E = einv + v*16;
        const float cx = E[0]*wxp + E[1]*wyp + E[2]*wzp + E[3];
        const float cy = E[4]*wxp + E[5]*wyp + E[6]*wzp + E[7];
        const float cz = E[8]*wxp + E[9]*wyp + E[10]*wzp + E[11];
        const float cw = E[12]*wxp + E[13]*wyp + E[14]*wzp + E[15];
        const float* Km = intr + v*16;
        const float px = Km[0]*cx + Km[1]*cy + Km[2]*cz + Km[3]*cw;
        const float py = Km[4]*cx + Km[5]*cy + Km[6]*cz + Km[7]*cw;
        const float pz = Km[8]*cx + Km[9]*cy + Km[10]*cz + Km[11]*cw;
        const float inv = pz + 1e-8f;
        float fx = px / inv, fy = py / inv;
        fx = fminf(fmaxf(fx, 0.0f), (float)(IMW-1));
        fy = fminf(fmaxf(fy, 0.0f), (float)(IMH-1));
        const int x0 = (int)floorf(fx), y0 = (int)floorf(fy);
        const int x1 = min(x0+1, IMW-1), y1 = min(y0+1, IMH-1);
        const int base = v*IMH*IMW;
        int4 o4; o4.x = (base + y0*IMW + x0) * NFEAT;
                 o4.y = (base + y0*IMW + x1) * NFEAT;
                 o4.z = (base + y1*IMW + x0) * NFEAT;
                 o4.w = (base + y1*IMW + x1) * NFEAT;
        *(int4*)&s_meta[p][0] = o4;
        s_meta[p][4] = fx - (float)x0;
        s_meta[p][5] = fy - (float)y0;
        s_meta[p][6] = cx; s_meta[p][7] = cy; s_meta[p][8] = cz;
        if (t == 0) {
            s_cdir[0] = E[0]*dx + E[1]*dy + E[2]*dz;
            s_cdir[1] = E[4]*dx + E[5]*dy + E[6]*dz;
            s_cdir[2] = E[8]*dx + E[9]*dy + E[10]*dz;
        }
    }
    __syncthreads();

    // ---- per-lane meta for this lane's A-row (sample wid*16+l15) ----
    const float* mrow = s_meta[wid*16 + l15];
    const int4 o4 = *(const int4*)mrow;
    const float wx = mrow[4], wy = mrow[5];
    const float w00 = (1.f-wx)*(1.f-wy), w01 = wx*(1.f-wy);
    const float w10 = (1.f-wx)*wy,       w11 = wx*wy;
    const float* t00 = feats + o4.x;
    const float* t01 = feats + o4.y;
    const float* t10 = feats + o4.z;
    const float* t11 = feats + o4.w;

    float img0 = 0.f, img1 = 0.f, img2 = 0.f;
    if (lg < 2) {
        const int i00 = (o4.x >> 8) * 3, i01 = (o4.y >> 8) * 3;
        const int i10 = (o4.z >> 8) * 3, i11 = (o4.w >> 8) * 3;
        img0 = 2.0f*(w00*images[i00+0] + w01*images[i01+0] + w10*images[i10+0] + w11*images[i11+0]) - 1.0f;
        img1 = 2.0f*(w00*images[i00+1] + w01*images[i01+1] + w10*images[i10+1] + w11*images[i11+1]) - 1.0f;
        img2 = 2.0f*(w00*images[i00+2] + w01*images[i01+2] + w10*images[i10+2] + w11*images[i11+2]) - 1.0f;
    }

    // ---- build A-fragments in-register (bilerp exactly this lane's dims) ----
    bf16x8 a1h[9], a1l[9];
    #pragma unroll
    for (int kc = 0; kc < 9; ++kc) {
        float f[8];
        const int fb = kc*32 + lg*8 - 16;          // feat index of this chunk
        if (kc == 0 && lg == 0) {
            f[0] = mrow[6]; f[1] = mrow[7]; f[2] = mrow[8];
            f[3] = s_cdir[0]; f[4] = s_cdir[1]; f[5] = s_cdir[2];
            f[6] = img0; f[7] = img1;
        } else if (kc == 0 && lg == 1) {
            f[0] = img2;
            #pragma unroll
            for (int i = 1; i < 8; ++i) f[i] = 0.0f;
        } else if (fb >= 256) {                    // k >= 272 zero-pad
            #pragma unroll
            for (int i = 0; i < 8; ++i) f[i] = 0.0f;
        } else {
            const float4 p00a = *reinterpret_cast<const float4*>(t00 + fb);
            const float4 p00b = *reinterpret_cast<const float4*>(t00 + fb + 4);
            const float4 p01a = *reinterpret_cast<const float4*>(t01 + fb);
            const float4 p01b = *reinterpret_cast<const float4*>(t01 + fb + 4);
            const float4 p10a = *reinterpret_cast<const float4*>(t10 + fb);
            const float4 p10b = *reinterpret_cast<const float4*>(t10 + fb + 4);
            const float4 p11a = *reinterpret_cast<const float4*>(t11 + fb);
            const float4 p11b = *reinterpret_cast<const float4*>(t11 + fb + 4);
            f[0] = w00*p00a.x + w01*p01a.x + w10*p10a.x + w11*p11a.x;
            f[1] = w00*p00a.y + w01*p01a.y + w10*p10a.y + w11*p11a.y;
            f[2] = w00*p00a.z + w01*p01a.z + w10*p10a.z + w11*p11a.z;
            f[3] = w00*p00a.w + w01*p01a.w + w10*p10a.w + w11*p11a.w;
            f[4] = w00*p00b.x + w01*p01b.x + w10*p10b.x + w11*p11b.x;
            f[5] = w00*p00b.y + w01*p01b.y + w10*p10b.y + w11*p11b.y;
            f[6] = w00*p00b.z + w01*p01b.z + w10*p10b.z + w11*p11b.z;
            f[7] = w00*p00b.w + w01*p01b.w + w10*p10b.w + w11*p11b.w;
        }
        splitpack(f, a1h[kc], a1l[kc]);
    }

    // ---- layer 1: 3-pass MFMA, h1 -> wave-private LDS (no barrier) ----
    const int hr0 = wid * 16 + lg * 4;
    const int koff = lg * 8;
    const unsigned short* wb1 = wsu + l15 * KU1 + koff;
    #pragma unroll 2
    for (int nt = 0; nt < 8; ++nt) {
        const unsigned short* wp = wb1 + nt * 16 * KU1;
        f32x4 acc = {0.f, 0.f, 0.f, 0.f};
        #pragma unroll
        for (int kc = 0; kc < 9; ++kc) {
            const bf16x8 bh = *(const bf16x8*)(wp + kc*32);
            const bf16x8 bl = *(const bf16x8*)(wp + W1LO + kc*32);
            acc = __builtin_amdgcn_mfma_f32_16x16x32_bf16(a1h[kc], bh, acc, 0, 0, 0);
            acc = __builtin_amdgcn_mfma_f32_16x16x32_bf16(a1l[kc], bh, acc, 0, 0, 0);
            acc = __builtin_amdgcn_mfma_f32_16x16x32_bf16(a1h[kc], bl, acc, 0, 0, 0);
        }
        const int ch = nt * 16 + l15;
        const float bb = b1[ch];
        #pragma unroll
        for (int j = 0; j < 4; ++j) {
            const float hv = fmaxf(acc[j] + bb, 0.0f);
            const unsigned short hh = bf16rne(hv);
            h1u[(hr0 + j) * H1S + ch]       = hh;
            h1u[(hr0 + j) * H1S + 128 + ch] = bf16rne(hv - bf16tof(hh));
        }
    }

    // ---- layer 2: A-frags from wave-private h1 (in-order LDS, no barrier) ----
    const unsigned short* rowb = h1u + (wid*16 + l15) * H1S;
    bf16x8 a2h[4], a2l[4];
    #pragma unroll
    for (int kc = 0; kc < 4; ++kc) {
        a2h[kc] = *(const bf16x8*)(rowb + kc*32 + koff);
        a2l[kc] = *(const bf16x8*)(rowb + 128 + kc*32 + koff);
    }
    float pr[4][4];
    #pragma unroll
    for (int j = 0; j < 4; ++j)
        #pragma unroll
        for (int q = 0; q < 4; ++q) pr[j][q] = 0.0f;

    const unsigned short* wb2 = wsu + W2OF + l15 * 128 + koff;
    #pragma unroll 2
    for (int nt = 0; nt < 8; ++nt) {
        const unsigned short* wp = wb2 + nt * 16 * 128;
        f32x4 acc = {0.f, 0.f, 0.f, 0.f};
        #pragma unroll
        for (int kc = 0; kc < 4; ++kc) {
            const bf16x8 bh = *(const bf16x8*)(wp + kc*32);
            const bf16x8 bl = *(const bf16x8*)(wp + W2LO + kc*32);
            acc = __builtin_amdgcn_mfma_f32_16x16x32_bf16(a2h[kc], bh, acc, 0, 0, 0);
            acc = __builtin_amdgcn_mfma_f32_16x16x32_bf16(a2l[kc], bh, acc, 0, 0, 0);
            acc = __builtin_amdgcn_mfma_f32_16x16x32_bf16(a2h[kc], bl, acc, 0, 0, 0);
        }
        const int ch = nt * 16 + l15;
        const float bb = b2[ch];
        const float4 wr = *reinterpret_cast<const float4*>(Wr + ch * 4);
        #pragma unroll
        for (int j = 0; j < 4; ++j) {
            const float hv = fmaxf(acc[j] + bb, 0.0f);
            pr[j][0] = fmaf(hv, wr.x, pr[j][0]);
            pr[j][1] = fmaf(hv, wr.y, pr[j][1]);
            pr[j][2] = fmaf(hv, wr.z, pr[j][2]);
            pr[j][3] = fmaf(hv, wr.w, pr[j][3]);
        }
    }
    // reduce across the 16 channel-slice lanes of each lg group
    #pragma unroll
    for (int m = 1; m <= 8; m <<= 1)
        #pragma unroll
        for (int j = 0; j < 4; ++j)
            #pragma unroll
            for (int q = 0; q < 4; ++q)
                pr[j][q] += __shfl_xor(pr[j][q], m, 64);
    if (l15 == 0) {
        #pragma unroll
        for (int j = 0; j < 4; ++j) {
            float4 o;
            o.x = pr[j][0]; o.y = pr[j][1]; o.z = pr[j][2]; o.w = pr[j][3];
            *reinterpret_cast<float4*>(pf + ((size_t)bid * 64 + hr0 + j) * 4) = o;
        }
    }
}

// ---- render: per-ray, lane = sample ----
__global__ __launch_bounds__(64)
void nerf_render(const float* __restrict__ pf,
                 const float* __restrict__ br,
                 float* __restrict__ out) {
    const int r = blockIdx.x;
    const int p = threadIdx.x;
    constexpr float STEP = (ZFAR - ZNEAR) / (NSAMP - 1);
    const float4 a = *reinterpret_cast<const float4*>(pf + ((r*2+0)*NSAMP + p)*4);
    const float4 b = *reinterpret_cast<const float4*>(pf + ((r*2+1)*NSAMP + p)*4);
    const float o0 = 0.5f*(a.x + b.x) + br[0];
    const float o1 = 0.5f*(a.y + b.y) + br[1];
    const float o2 = 0.5f*(a.z + b.z) + br[2];
    const float o3 = 0.5f*(a.w + b.w) + br[3];
    const float c0 = 1.0f/(1.0f + __expf(-o0));
    const float c1 = 1.0f/(1.0f + __expf(-o1));
    const float c2 = 1.0f/(1.0f + __expf(-o2));
    const float dens = fmaxf(o3, 0.0f);
    const float zp = ZNEAR + p * STEP;
    const float zn = ZNEAR + (p+1) * STEP;
    const float dlast = (ZNEAR + 63*STEP) - (ZNEAR + 62*STEP);
    const float dist = (p == NSAMP-1) ? dlast : (zn - zp);
    const float alpha = 1.0f - __expf(-dens*dist);
    float scan = 1.0f - alpha + 1e-10f;
    #pragma unroll
    for (int off = 1; off < 64; off <<= 1) {
        const float vsh = __shfl_up(scan, off, 64);
        if (p >= off) scan *= vsh;
    }
    float trans = __shfl_up(scan, 1, 64);
    if (p == 0) trans = 1.0f;
    const float w = alpha * trans;
    float s0 = w*c0, s1 = w*c1, s2 = w*c2, sd = w*zp;
    #pragma unroll
    for (int m = 32; m > 0; m >>= 1) {
        s0 += __shfl_xor(s0, m, 64);
        s1 += __shfl_xor(s1, m, 64);
        s2 += __shfl_xor(s2, m, 64);
        sd += __shfl_xor(sd, m, 64);
    }
    if (p == 0) {
        out[r*3+0] = s0; out[r*3+1] = s1; out[r*3+2] = s2;
        out[NRAYS*3 + r] = sd;
    }
}

extern "C" void kernel_launch(void* const* d_in, const int* in_sizes, int n_in,
                              void* d_out, int out_size, void* d_ws, size_t ws_size,
                              hipStream_t stream) {
    const float* rayo   = (const float*)d_in[0];
    const float* rayd   = (const float*)d_in[1];
    const float* images = (const float*)d_in[2];
    const float* intr   = (const float*)d_in[3];
    const float* einv   = (const float*)d_in[4];
    const float* feats  = (const float*)d_in[5];
    const float* W1     = (const float*)d_in[6];
    const float* b1     = (const float*)d_in[7];
    const float* W2     = (const float*)d_in[8];
    const float* b2     = (const float*)d_in[9];
    const float* Wr     = (const float*)d_in[10];
    const float* br     = (const float*)d_in[11];
    float* out = (float*)d_out;
    unsigned short* wsu = (unsigned short*)d_ws;                 // W split planes
    float* pf = (float*)((char*)d_ws + 262144);                  // per-(ray,view) partials

    hipLaunchKernelGGL(nerf_prep, dim3(208), dim3(256), 0, stream, W1, W2, wsu);
    hipLaunchKernelGGL(nerf_main, dim3(NRAYS*2), dim3(256), 0, stream,
                       rayo, rayd, images, intr, einv, feats, b1, b2, Wr, wsu, pf);
    hipLaunchKernelGGL(nerf_render, dim3(NRAYS), dim3(64), 0, stream, pf, br, out);
}

// Round 7
// 96.854 us; speedup vs baseline: 1.7453x; 1.7453x over previous
//
#include <hip/hip_runtime.h>
#include <math.h>

#define NRAYS 512
#define NSAMP 64
#define IMH 480
#define IMW 640
#define NFEAT 256
#define ZNEAR 0.7f
#define ZFAR 1.5f
#define KU1 288          // W1 row length (ushorts): k-map 0-8 meta, 9-15 zero, 16-271 feats, 272-287 zero
#define W1LO 36864       // ushort offset of W1 lo plane
#define W2OF 73728       // ushort offset of W2 hi plane
#define W2LO 16384       // relative ushort offset of W2 lo plane
#define STGS 36          // staging row stride (u32): 16B-aligned, 2-way-bank
#define H1S 132          // h1 packed row stride (u32): 16B-aligned, 2-way-bank

typedef __attribute__((ext_vector_type(8))) short bf16x8;
typedef __attribute__((ext_vector_type(4))) float f32x4;

__device__ __forceinline__ unsigned short bf16rne(float f) {
    unsigned int u = __builtin_bit_cast(unsigned int, f);
    unsigned int r = (u + 0x7FFFu + ((u >> 16) & 1u)) >> 16;
    return (unsigned short)r;
}
__device__ __forceinline__ float bf16tof(unsigned short h) {
    unsigned int u = ((unsigned int)h) << 16;
    return __builtin_bit_cast(float, u);
}
__device__ __forceinline__ unsigned int packsplit(float v) {
    const unsigned short h = bf16rne(v);
    const unsigned short l = bf16rne(v - bf16tof(h));
    return (((unsigned int)h) << 16) | (unsigned int)l;
}
__device__ __forceinline__ void unpack8(uint4 a, uint4 b, bf16x8& hi, bf16x8& lo) {
    union { bf16x8 v; unsigned short u[8]; } H, L;
    const unsigned int w[8] = {a.x, a.y, a.z, a.w, b.x, b.y, b.z, b.w};
    #pragma unroll
    for (int i = 0; i < 8; ++i) {
        H.u[i] = (unsigned short)(w[i] >> 16);
        L.u[i] = (unsigned short)(w[i] & 0xFFFFu);
    }
    hi = H.v; lo = L.v;
}

// ---- prep: transpose + bf16-split W1 -> [128][288] (k-map above) and W2 -> [128][128] ----
__global__ __launch_bounds__(256)
void nerf_prep(const float* __restrict__ W1, const float* __restrict__ W2,
               unsigned short* __restrict__ wsu) {
    const int i = blockIdx.x * 256 + threadIdx.x;
    if (i < 36864) {
        const int n = i / KU1, k = i % KU1;
        float val = 0.0f;
        if (k < 9) val = W1[k * 128 + n];
        else if (k >= 16 && k < 272) val = W1[(k - 7) * 128 + n];
        const unsigned short h = bf16rne(val);
        wsu[n * KU1 + k] = h;
        wsu[W1LO + n * KU1 + k] = bf16rne(val - bf16tof(h));
    } else if (i < 53248) {
        const int j = i - 36864;
        const int n = j >> 7, k = j & 127;
        const float val = W2[k * 128 + n];
        const unsigned short h = bf16rne(val);
        wsu[W2OF + n * 128 + k] = h;
        wsu[W2OF + W2LO + n * 128 + k] = bf16rne(val - bf16tof(h));
    }
}

// ---- main: block = (ray,view), 256 thr = 4 waves, wave owns 16 samples.
// Gather: per-wave LDS transpose staging (coalesced 64B cluster loads, packed
// u32 split-bf16), wave-private -> no barriers. MLP: 3-pass split-bf16 MFMA,
// B streamed from global (L2), h1 packed u32 wave-private in LDS.
__global__ __launch_bounds__(256, 3)
void nerf_main(const float* __restrict__ rayo,
               const float* __restrict__ rayd,
               const float* __restrict__ images,
               const float* __restrict__ intr,
               const float* __restrict__ einv,
               const float* __restrict__ feats,
               const float* __restrict__ b1,
               const float* __restrict__ b2,
               const float* __restrict__ Wr,
               const unsigned short* __restrict__ wsu,
               float* __restrict__ pf) {
    __shared__ float s_meta[NSAMP][12];              // int4 o4 | wx wy | cam xyz
    __shared__ float s_cdir[4];
    __shared__ unsigned int h1p[NSAMP * H1S];        // 33,792 B (packed hi|lo)
    __shared__ unsigned int stgw[4][16 * STGS];      // 9,216 B (per-wave transpose staging)

    const int t = threadIdx.x;
    const int bid = blockIdx.x;
    const int r = bid >> 1, v = bid & 1;
    const int lane = t & 63;
    const int wid = __builtin_amdgcn_readfirstlane(t >> 6);
    const int l15 = lane & 15;
    const int lg  = lane >> 4;
    const int sq  = lane >> 2;        // gather: sample-within-wave
    const int qq  = lane & 3;         // gather: dim-quad
    constexpr float STEP = (ZFAR - ZNEAR) / (NSAMP - 1);

    // ---- projection prep: one thread per sample ----
    if (t < NSAMP) {
        const int p = t;
        const float ox = rayo[r*3+0], oy = rayo[r*3+1], oz = rayo[r*3+2];
        const float dx = rayd[r*3+0], dy = rayd[r*3+1], dz = rayd[r*3+2];
        const float z = ZNEAR + p * STEP;
        const float wxp = ox + z*dx, wyp = oy + z*dy, wzp = oz + z*dz;
        const float* E = einv + v*16;
        const float cx = E[0]*wxp + E[1]*wyp + E[2]*wzp + E[3];
        const float cy = E[4]*wxp + E[5]*wyp + E[6]*wzp + E[7];
        const float cz = E[8]*wxp + E[9]*wyp + E[10]*wzp + E[11];
        const float cw = E[12]*wxp + E[13]*wyp + E[14]*wzp + E[15];
        const float* Km = intr + v*16;
        const float px = Km[0]*cx + Km[1]*cy + Km[2]*cz + Km[3]*cw;
        const float py = Km[4]*cx + Km[5]*cy + Km[6]*cz + Km[7]*cw;
        const float pz = Km[8]*cx + Km[9]*cy + Km[10]*cz + Km[11]*cw;
        const float inv = pz + 1e-8f;
        float fx = px / inv, fy = py / inv;
        fx = fminf(fmaxf(fx, 0.0f), (float)(IMW-1));
        fy = fminf(fmaxf(fy, 0.0f), (float)(IMH-1));
        const int x0 = (int)floorf(fx), y0 = (int)floorf(fy);
        const int x1 = min(x0+1, IMW-1), y1 = min(y0+1, IMH-1);
        const int base = v*IMH*IMW;
        int4 o4; o4.x = (base + y0*IMW + x0) * NFEAT;
                 o4.y = (base + y0*IMW + x1) * NFEAT;
                 o4.z = (base + y1*IMW + x0) * NFEAT;
                 o4.w = (base + y1*IMW + x1) * NFEAT;
        *(int4*)&s_meta[p][0] = o4;
        s_meta[p][4] = fx - (float)x0;
        s_meta[p][5] = fy - (float)y0;
        s_meta[p][6] = cx; s_meta[p][7] = cy; s_meta[p][8] = cz;
        if (t == 0) {
            s_cdir[0] = E[0]*dx + E[1]*dy + E[2]*dz;
            s_cdir[1] = E[4]*dx + E[5]*dy + E[6]*dz;
            s_cdir[2] = E[8]*dx + E[9]*dy + E[10]*dz;
        }
    }
    __syncthreads();

    // ---- gather meta for this lane's staging sample (wid*16 + sq) ----
    const float* mg = s_meta[wid*16 + sq];
    const int4 og = *(const int4*)mg;
    const float wx = mg[4], wy = mg[5];
    const float w00 = (1.f-wx)*(1.f-wy), w01 = wx*(1.f-wy);
    const float w10 = (1.f-wx)*wy,       w11 = wx*wy;
    const float* t00 = feats + og.x;
    const float* t01 = feats + og.y;
    const float* t10 = feats + og.z;
    const float* t11 = feats + og.w;

    float ia = 0.f, ib = 0.f;                 // qq==1: img0,img1 ; qq==2: img2
    if (qq == 1 || qq == 2) {
        const int i00 = (og.x >> 8) * 3, i01 = (og.y >> 8) * 3;
        const int i10 = (og.z >> 8) * 3, i11 = (og.w >> 8) * 3;
        if (qq == 1) {
            ia = 2.0f*(w00*images[i00+0] + w01*images[i01+0] + w10*images[i10+0] + w11*images[i11+0]) - 1.0f;
            ib = 2.0f*(w00*images[i00+1] + w01*images[i01+1] + w10*images[i10+1] + w11*images[i11+1]) - 1.0f;
        } else {
            ia = 2.0f*(w00*images[i00+2] + w01*images[i01+2] + w10*images[i10+2] + w11*images[i11+2]) - 1.0f;
        }
    }

    // ---- gather + transpose: build A-fragments chunk by chunk ----
    unsigned int* stg = &stgw[wid][0];
    bf16x8 a1h[9], a1l[9];
    #pragma unroll
    for (int kc = 0; kc < 9; ++kc) {
        #pragma unroll
        for (int sub = 0; sub < 2; ++sub) {
            float f[4];
            if (kc == 0 && sub == 0) {
                if (qq == 0)      { f[0]=mg[6]; f[1]=mg[7]; f[2]=mg[8]; f[3]=s_cdir[0]; }
                else if (qq == 1) { f[0]=s_cdir[1]; f[1]=s_cdir[2]; f[2]=ia; f[3]=ib; }
                else if (qq == 2) { f[0]=ia; f[1]=0.f; f[2]=0.f; f[3]=0.f; }
                else              { f[0]=0.f; f[1]=0.f; f[2]=0.f; f[3]=0.f; }
            } else if (kc == 8 && sub == 1) {
                f[0]=0.f; f[1]=0.f; f[2]=0.f; f[3]=0.f;
            } else {
                const int f0 = kc*32 + sub*16 + qq*4 - 16;
                const float4 p00 = *reinterpret_cast<const float4*>(t00 + f0);
                const float4 p01 = *reinterpret_cast<const float4*>(t01 + f0);
                const float4 p10 = *reinterpret_cast<const float4*>(t10 + f0);
                const float4 p11 = *reinterpret_cast<const float4*>(t11 + f0);
                f[0] = w00*p00.x + w01*p01.x + w10*p10.x + w11*p11.x;
                f[1] = w00*p00.y + w01*p01.y + w10*p10.y + w11*p11.y;
                f[2] = w00*p00.z + w01*p01.z + w10*p10.z + w11*p11.z;
                f[3] = w00*p00.w + w01*p01.w + w10*p10.w + w11*p11.w;
            }
            uint4 uu;
            uu.x = packsplit(f[0]); uu.y = packsplit(f[1]);
            uu.z = packsplit(f[2]); uu.w = packsplit(f[3]);
            *reinterpret_cast<uint4*>(stg + sq*STGS + sub*16 + qq*4) = uu;
        }
        // wave-private transpose read (in-order DS, no barrier)
        const uint4 ua = *reinterpret_cast<const uint4*>(stg + l15*STGS + lg*8);
        const uint4 ub = *reinterpret_cast<const uint4*>(stg + l15*STGS + lg*8 + 4);
        unpack8(ua, ub, a1h[kc], a1l[kc]);
    }

    // ---- layer 1: 3-pass MFMA, h1 packed u32 -> wave-private LDS ----
    const int hrbase = wid*16 + lg*4;
    const unsigned short* wb1 = wsu + l15 * KU1 + lg*8;
    #pragma unroll 2
    for (int nt = 0; nt < 8; ++nt) {
        const unsigned short* wp = wb1 + nt * 16 * KU1;
        f32x4 acc = {0.f, 0.f, 0.f, 0.f};
        #pragma unroll
        for (int kc = 0; kc < 9; ++kc) {
            const bf16x8 bh = *(const bf16x8*)(wp + kc*32);
            const bf16x8 bl = *(const bf16x8*)(wp + W1LO + kc*32);
            acc = __builtin_amdgcn_mfma_f32_16x16x32_bf16(a1h[kc], bh, acc, 0, 0, 0);
            acc = __builtin_amdgcn_mfma_f32_16x16x32_bf16(a1l[kc], bh, acc, 0, 0, 0);
            acc = __builtin_amdgcn_mfma_f32_16x16x32_bf16(a1h[kc], bl, acc, 0, 0, 0);
        }
        const int ch = nt * 16 + l15;
        const float bb = b1[ch];
        #pragma unroll
        for (int j = 0; j < 4; ++j) {
            const float hv = fmaxf(acc[j] + bb, 0.0f);
            h1p[(hrbase + j) * H1S + ch] = packsplit(hv);
        }
    }

    // ---- layer 2: A-frags from wave-private packed h1 (no barrier) ----
    const unsigned int* h1row = h1p + (wid*16 + l15) * H1S;
    bf16x8 a2h[4], a2l[4];
    #pragma unroll
    for (int kc = 0; kc < 4; ++kc) {
        const uint4 ua = *reinterpret_cast<const uint4*>(h1row + kc*32 + lg*8);
        const uint4 ub = *reinterpret_cast<const uint4*>(h1row + kc*32 + lg*8 + 4);
        unpack8(ua, ub, a2h[kc], a2l[kc]);
    }
    float pr[4][4];
    #pragma unroll
    for (int j = 0; j < 4; ++j)
        #pragma unroll
        for (int q = 0; q < 4; ++q) pr[j][q] = 0.0f;

    const unsigned short* wb2 = wsu + W2OF + l15 * 128 + lg*8;
    #pragma unroll 2
    for (int nt = 0; nt < 8; ++nt) {
        const unsigned short* wp = wb2 + nt * 16 * 128;
        f32x4 acc = {0.f, 0.f, 0.f, 0.f};
        #pragma unroll
        for (int kc = 0; kc < 4; ++kc) {
            const bf16x8 bh = *(const bf16x8*)(wp + kc*32);
            const bf16x8 bl = *(const bf16x8*)(wp + W2LO + kc*32);
            acc = __builtin_amdgcn_mfma_f32_16x16x32_bf16(a2h[kc], bh, acc, 0, 0, 0);
            acc = __builtin_amdgcn_mfma_f32_16x16x32_bf16(a2l[kc], bh, acc, 0, 0, 0);
            acc = __builtin_amdgcn_mfma_f32_16x16x32_bf16(a2h[kc], bl, acc, 0, 0, 0);
        }
        const int ch = nt * 16 + l15;
        const float bb = b2[ch];
        const float4 wr = *reinterpret_cast<const float4*>(Wr + ch * 4);
        #pragma unroll
        for (int j = 0; j < 4; ++j) {
            const float hv = fmaxf(acc[j] + bb, 0.0f);
            pr[j][0] = fmaf(hv, wr.x, pr[j][0]);
            pr[j][1] = fmaf(hv, wr.y, pr[j][1]);
            pr[j][2] = fmaf(hv, wr.z, pr[j][2]);
            pr[j][3] = fmaf(hv, wr.w, pr[j][3]);
        }
    }
    // reduce across the 16 channel-slice lanes of each lg group
    #pragma unroll
    for (int m = 1; m <= 8; m <<= 1)
        #pragma unroll
        for (int j = 0; j < 4; ++j)
            #pragma unroll
            for (int q = 0; q < 4; ++q)
                pr[j][q] += __shfl_xor(pr[j][q], m, 64);
    if (l15 == 0) {
        #pragma unroll
        for (int j = 0; j < 4; ++j) {
            float4 o;
            o.x = pr[j][0]; o.y = pr[j][1]; o.z = pr[j][2]; o.w = pr[j][3];
            *reinterpret_cast<float4*>(pf + ((size_t)bid * 64 + hrbase + j) * 4) = o;
        }
    }
}

// ---- render: per-ray, lane = sample ----
__global__ __launch_bounds__(64)
void nerf_render(const float* __restrict__ pf,
                 const float* __restrict__ br,
                 float* __restrict__ out) {
    const int r = blockIdx.x;
    const int p = threadIdx.x;
    constexpr float STEP = (ZFAR - ZNEAR) / (NSAMP - 1);
    const float4 a = *reinterpret_cast<const float4*>(pf + ((r*2+0)*NSAMP + p)*4);
    const float4 b = *reinterpret_cast<const float4*>(pf + ((r*2+1)*NSAMP + p)*4);
    const float o0 = 0.5f*(a.x + b.x) + br[0];
    const float o1 = 0.5f*(a.y + b.y) + br[1];
    const float o2 = 0.5f*(a.z + b.z) + br[2];
    const float o3 = 0.5f*(a.w + b.w) + br[3];
    const float c0 = 1.0f/(1.0f + __expf(-o0));
    const float c1 = 1.0f/(1.0f + __expf(-o1));
    const float c2 = 1.0f/(1.0f + __expf(-o2));
    const float dens = fmaxf(o3, 0.0f);
    const float zp = ZNEAR + p * STEP;
    const float zn = ZNEAR + (p+1) * STEP;
    const float dlast = (ZNEAR + 63*STEP) - (ZNEAR + 62*STEP);
    const float dist = (p == NSAMP-1) ? dlast : (zn - zp);
    const float alpha = 1.0f - __expf(-dens*dist);
    float scan = 1.0f - alpha + 1e-10f;
    #pragma unroll
    for (int off = 1; off < 64; off <<= 1) {
        const float vsh = __shfl_up(scan, off, 64);
        if (p >= off) scan *= vsh;
    }
    float trans = __shfl_up(scan, 1, 64);
    if (p == 0) trans = 1.0f;
    const float w = alpha * trans;
    float s0 = w*c0, s1 = w*c1, s2 = w*c2, sd = w*zp;
    #pragma unroll
    for (int m = 32; m > 0; m >>= 1) {
        s0 += __shfl_xor(s0, m, 64);
        s1 += __shfl_xor(s1, m, 64);
        s2 += __shfl_xor(s2, m, 64);
        sd += __shfl_xor(sd, m, 64);
    }
    if (p == 0) {
        out[r*3+0] = s0; out[r*3+1] = s1; out[r*3+2] = s2;
        out[NRAYS*3 + r] = sd;
    }
}

extern "C" void kernel_launch(void* const* d_in, const int* in_sizes, int n_in,
                              void* d_out, int out_size, void* d_ws, size_t ws_size,
                              hipStream_t stream) {
    const float* rayo   = (const float*)d_in[0];
    const float* rayd   = (const float*)d_in[1];
    const float* images = (const float*)d_in[2];
    const float* intr   = (const float*)d_in[3];
    const float* einv   = (const float*)d_in[4];
    const float* feats  = (const float*)d_in[5];
    const float* W1     = (const float*)d_in[6];
    const float* b1     = (const float*)d_in[7];
    const float* W2     = (const float*)d_in[8];
    const float* b2     = (const float*)d_in[9];
    const float* Wr     = (const float*)d_in[10];
    const float* br     = (const float*)d_in[11];
    float* out = (float*)d_out;
    unsigned short* wsu = (unsigned short*)d_ws;                 // W split planes (213 KB)
    float* pf = (float*)((char*)d_ws + 262144);                  // per-(ray,view) partials (1 MB)

    hipLaunchKernelGGL(nerf_prep, dim3(208), dim3(256), 0, stream, W1, W2, wsu);
    hipLaunchKernelGGL(nerf_main, dim3(NRAYS*2), dim3(256), 0, stream,
                       rayo, rayd, images, intr, einv, feats, b1, b2, Wr, wsu, pf);
    hipLaunchKernelGGL(nerf_render, dim3(NRAYS), dim3(64), 0, stream, pf, br, out);
}